// Round 3
// baseline (2140.187 us; speedup 1.0000x reference)
//
#include <hip/hip_runtime.h>
#include <hip/hip_bf16.h>

typedef __attribute__((ext_vector_type(8))) short bf16x8;
typedef __attribute__((ext_vector_type(4))) float f32x4;

#define MFMA(a,b,c) __builtin_amdgcn_mfma_f32_16x16x32_bf16(a,b,c,0,0,0)

__device__ __forceinline__ short f2b(float v){
  __hip_bfloat16 b = __float2bfloat16(v);
  return *reinterpret_cast<short*>(&b);
}
__device__ __forceinline__ float b2f(short s){
  __hip_bfloat16 b;
  *reinterpret_cast<short*>(&b) = s;
  return __bfloat162float(b);
}
// bool arrays may arrive as uint8 / int32 / float32 depending on harness upload.
__device__ __forceinline__ bool rd_mask(const void* m, long i, int flag){
  if (flag==1) return ((const int*)m)[i] != 0;
  if (flag==2) return ((const float*)m)[i] != 0.0f;
  return ((const unsigned char*)m)[i] != 0;
}

// detect bool-array storage; mask0[i][13] (center tap) is always true.
__global__ void k_detect(const void* __restrict__ mask, int* flag, float* ce){
  if (threadIdx.x==0 && blockIdx.x==0){
    const int* mi = (const int*)mask;
    const float* mf = (const float*)mask;
    bool all_i=true, all_f=true;
    for (int i=0;i<100;i++){
      if (mi[i*27+13] != 1) all_i=false;
      if (mf[i*27+13] != 1.0f) all_f=false;
    }
    *flag = all_i ? 1 : (all_f ? 2 : 0);
    *ce = 0.0f;
  }
}

// Pack all weights (f32) into bf16 MFMA B-fragment layout.
// conv frags: [k][ct4][ks2][lane64][e8]; dec: [ks4][ct4][lane][e] (cin padded 72->128);
// wl0: [cb8][ct4][ks2][lane][e]; wl1: [ct16][ks2][lane][e] (col 255 zero-padded).
__global__ __launch_bounds__(256) void k_prep(
    const float* __restrict__ Wdec, const float* __restrict__ Wb1,
    const float* __restrict__ Wb2, const float* __restrict__ Wp0,
    const float* __restrict__ Wp1, const float* __restrict__ Wl0,
    const float* __restrict__ Wl1,
    short* __restrict__ wdecf, short* __restrict__ wconvf,
    short* __restrict__ wl0f, short* __restrict__ wl1f)
{
  int i = blockIdx.x*256 + threadIdx.x;
  if (i < 442368){
    int ci = i / 110592, r = i % 110592;
    int e = r&7, ln=(r>>3)&63, ks=(r>>9)&1, ct=(r>>10)&3, k=r>>12;
    int cin = ks*32 + (ln>>4)*8 + e, cout = ct*16 + (ln&15);
    const float* W = ci==0?Wb1: ci==1?Wb2: ci==2?Wp0:Wp1;
    wconvf[i] = f2b(W[(k*64+cin)*64 + cout]);
  } else if (i < 450560){
    int r = i - 442368;
    int e=r&7, ln=(r>>3)&63, ct=(r>>9)&3, ks=(r>>11)&3;
    int cin = ks*32 + (ln>>4)*8 + e, cout = ct*16 + (ln&15);
    wdecf[r] = f2b(cin<72 ? Wdec[cin*64+cout] : 0.f);
  } else if (i < 483328){
    int r = i - 450560;
    int e=r&7, ln=(r>>3)&63, ks=(r>>9)&1, ct=(r>>10)&3, cb=(r>>12)&7;
    int cin = ks*32+(ln>>4)*8+e, col = cb*64+ct*16+(ln&15);
    wl0f[r] = f2b(Wl0[cin*512 + col]);
  } else if (i < 499712){
    int r = i - 483328;
    int e=r&7, ln=(r>>3)&63, ks=(r>>9)&1, ct=(r>>10)&15;
    int cin = ks*32+(ln>>4)*8+e, col = ct*16+(ln&15);
    wl1f[r] = f2b(col<255 ? Wl1[cin*255+col] : 0.f);
  }
}

__global__ void k_inv_init(int* __restrict__ inv, int total){
  int i = blockIdx.x*256 + threadIdx.x;
  if (i < total) inv[i] = -1;
}
__global__ void k_inv_fill(const int* __restrict__ sel, int* __restrict__ inv, int M_){
  int m = blockIdx.x*256 + threadIdx.x;
  if (m < M_) inv[sel[m]] = m;
}

// dec: x = prelu(concat(cur_rec_F, bins1_f) @ Wdec + b, a) ; K padded 72->128
__global__ __launch_bounds__(256) void k_dec(
    const float* __restrict__ xf, const float* __restrict__ bf1,
    const short* __restrict__ wfrag, const float* __restrict__ bias,
    const float* __restrict__ alphap, short* __restrict__ outb, int n)
{
  __shared__ bf16x8 Au[2048];  // 128 rows x 16 units, XOR-swizzled
  int t=threadIdx.x, lane=t&63, wid=t>>6;
  long row0 = (long)blockIdx.x*128;
  int sr=t>>1, sh=t&1;
  long r = row0+sr;
  bf16x8 u[8];
  #pragma unroll
  for (int j=0;j<8;j++) u[j] = bf16x8{0,0,0,0,0,0,0,0};
  if (r<n){
    if (sh==0){
      const f32x4* s = (const f32x4*)(xf + r*64);
      #pragma unroll
      for (int j=0;j<8;j++){
        f32x4 v0 = s[2*j], v1 = s[2*j+1];
        bf16x8 b;
        b[0]=f2b(v0[0]); b[1]=f2b(v0[1]); b[2]=f2b(v0[2]); b[3]=f2b(v0[3]);
        b[4]=f2b(v1[0]); b[5]=f2b(v1[1]); b[6]=f2b(v1[2]); b[7]=f2b(v1[3]);
        u[j]=b;
      }
    } else {
      const float* s = bf1 + r*8;
      bf16x8 b;
      #pragma unroll
      for (int j=0;j<8;j++) b[j]=f2b(s[j]);
      u[0]=b;
    }
  }
  int ub = sr*16 + sh*8;
  #pragma unroll
  for (int j=0;j<8;j++) Au[(ub+j)^(sr&7)] = u[j];
  __syncthreads();
  const bf16x8* wf = (const bf16x8*)wfrag;
  f32x4 acc[2][4];
  #pragma unroll
  for (int a_=0;a_<2;a_++)
  #pragma unroll
  for (int b_=0;b_<4;b_++) acc[a_][b_] = f32x4{0.f,0.f,0.f,0.f};
  #pragma unroll
  for (int ks=0;ks<4;ks++){
    bf16x8 a[2];
    #pragma unroll
    for (int rt=0;rt<2;rt++){
      int rr = wid*32 + rt*16 + (lane&15);
      a[rt] = Au[(rr*16 + ks*4 + (lane>>4)) ^ (rr&7)];
    }
    #pragma unroll
    for (int ct=0;ct<4;ct++){
      bf16x8 b = wf[(ks*4 + ct)*64 + lane];
      #pragma unroll
      for (int rt=0;rt<2;rt++) acc[rt][ct] = MFMA(a[rt], b, acc[rt][ct]);
    }
  }
  float al = alphap[0];
  #pragma unroll
  for (int rt=0;rt<2;rt++)
  #pragma unroll
  for (int ct=0;ct<4;ct++){
    int col = ct*16+(lane&15);
    float bc = bias[col];
    #pragma unroll
    for (int q=0;q<4;q++){
      long rr = row0 + wid*32 + rt*16 + (lane>>4)*4 + q;
      if (rr<n){
        float v = acc[rt][ct][q] + bc;
        v = v>=0.f? v : al*v;
        outb[rr*64+col] = f2b(v);
      }
    }
  }
}

// ---------------------------------------------------------------------------
// Barrier-free sparse conv: each wave owns 32 rows x 64 cols. A-fragments are
// gathered DIRECTLY from global into registers (lane l reads 16B of row
// (l&15) at byte offset ks*64+(l>>4)*16 -- exactly the mfma_16x16x32 A
// layout). B-fragments read from packed weights (8KB/tap hot set -> L1).
// Software pipeline: A-gather 1 tap ahead, nbr/mask 2 taps ahead. No LDS.
// ---------------------------------------------------------------------------
__global__ __launch_bounds__(256) void k_conv(
    const short* __restrict__ xin, const int* __restrict__ nbr,
    const void* __restrict__ maskp, const short* __restrict__ wfrag,
    const float* __restrict__ bias, const float* __restrict__ alphap,
    const short* __restrict__ resid, short* __restrict__ outb,
    float* __restrict__ outf, int n, const int* __restrict__ flagp)
{
  int flag = *flagp;
  int t=threadIdx.x, lane=t&63, wid=t>>6;
  long wrow0 = (long)blockIdx.x*128 + wid*32;
  long rA0 = wrow0 + (lane&15), rA1 = rA0 + 16;
  bool vA0 = rA0 < n, vA1 = rA1 < n;
  int uoff = lane>>4;
  const bf16x8* wf = (const bf16x8*)wfrag;

  int nb_c0, nb_c1, nb_n0, nb_n1;
  bool m_c0, m_c1, m_n0, m_n1;
  bf16x8 an[2][2];
  const bf16x8 z = {0,0,0,0,0,0,0,0};

  // nbr/mask for tap 0 and 1
  nb_c0 = vA0 ? nbr[rA0*27+0] : 0;  m_c0 = vA0 && rd_mask(maskp, rA0*27+0, flag);
  nb_c1 = vA1 ? nbr[rA1*27+0] : 0;  m_c1 = vA1 && rd_mask(maskp, rA1*27+0, flag);
  // A for tap 0
  {
    const bf16x8* s0 = (const bf16x8*)(xin + (long)nb_c0*64) + uoff;
    const bf16x8* s1 = (const bf16x8*)(xin + (long)nb_c1*64) + uoff;
    an[0][0] = m_c0 ? s0[0] : z;  an[0][1] = m_c0 ? s0[4] : z;
    an[1][0] = m_c1 ? s1[0] : z;  an[1][1] = m_c1 ? s1[4] : z;
  }
  nb_n0 = vA0 ? nbr[rA0*27+1] : 0;  m_n0 = vA0 && rd_mask(maskp, rA0*27+1, flag);
  nb_n1 = vA1 ? nbr[rA1*27+1] : 0;  m_n1 = vA1 && rd_mask(maskp, rA1*27+1, flag);

  f32x4 acc[2][4];
  #pragma unroll
  for (int a_=0;a_<2;a_++)
  #pragma unroll
  for (int b_=0;b_<4;b_++) acc[a_][b_] = f32x4{0.f,0.f,0.f,0.f};

  for (int k=0;k<27;k++){
    bf16x8 ac[2][2];
    ac[0][0]=an[0][0]; ac[0][1]=an[0][1]; ac[1][0]=an[1][0]; ac[1][1]=an[1][1];
    if (k<26){
      // issue next tap's gathers (addresses already resident)
      const bf16x8* s0 = (const bf16x8*)(xin + (long)nb_n0*64) + uoff;
      const bf16x8* s1 = (const bf16x8*)(xin + (long)nb_n1*64) + uoff;
      an[0][0] = m_n0 ? s0[0] : z;  an[0][1] = m_n0 ? s0[4] : z;
      an[1][0] = m_n1 ? s1[0] : z;  an[1][1] = m_n1 ? s1[4] : z;
      if (k<25){
        nb_n0 = vA0 ? nbr[rA0*27+k+2] : 0;  m_n0 = vA0 && rd_mask(maskp, rA0*27+k+2, flag);
        nb_n1 = vA1 ? nbr[rA1*27+k+2] : 0;  m_n1 = vA1 && rd_mask(maskp, rA1*27+k+2, flag);
      }
    }
    const bf16x8* wfk = wf + (long)k*512;
    #pragma unroll
    for (int ct=0;ct<4;ct++){
      bf16x8 b0 = wfk[(ct*2+0)*64 + lane];
      bf16x8 b1 = wfk[(ct*2+1)*64 + lane];
      acc[0][ct] = MFMA(ac[0][0], b0, acc[0][ct]);
      acc[1][ct] = MFMA(ac[1][0], b0, acc[1][ct]);
      acc[0][ct] = MFMA(ac[0][1], b1, acc[0][ct]);
      acc[1][ct] = MFMA(ac[1][1], b1, acc[1][ct]);
    }
  }
  float al = alphap ? alphap[0] : 0.f;
  #pragma unroll
  for (int rt=0;rt<2;rt++)
  #pragma unroll
  for (int ct=0;ct<4;ct++){
    int col = ct*16 + (lane&15);
    float bc = bias[col];
    #pragma unroll
    for (int q=0;q<4;q++){
      long rr = wrow0 + rt*16 + (lane>>4)*4 + q;
      if (rr < n){
        float v = acc[rt][ct][q] + bc;
        if (resid) v += b2f(resid[rr*64+col]);
        if (alphap) v = v>=0.f ? v : al*v;
        outb[rr*64+col] = f2b(v);
        if (outf) outf[rr*64+col] = v;
      }
    }
  }
}

// fused p = r0 @ Wl0 + bl0 (64->512) + child-gather scatter to tmp[M,64].
__global__ __launch_bounds__(256) void k_linscatter(
    const short* __restrict__ r0b, const short* __restrict__ wl0f,
    const float* __restrict__ bl0, const int* __restrict__ inv,
    short* __restrict__ tmpb, int n)
{
  __shared__ bf16x8 Au[1024];
  int t=threadIdx.x, lane=t&63, wid=t>>6, wrow=wid>>1, wcol=wid&1;
  long row0=(long)blockIdx.x*128;
  int sr=t>>1, sh=t&1;
  long r=row0+sr;
  bf16x8 z = {0,0,0,0,0,0,0,0};
  const bf16x8* s = (const bf16x8*)(r0b + r*64 + sh*32);
  int ub = sr*8+sh*4;
  #pragma unroll
  for (int j=0;j<4;j++) Au[(ub+j)^(sr&7)] = (r<n)? s[j] : z;
  __syncthreads();
  bf16x8 a[4][2];
  #pragma unroll
  for (int rt=0;rt<4;rt++){
    int rr = wrow*64 + rt*16 + (lane&15);
    #pragma unroll
    for (int ks=0;ks<2;ks++)
      a[rt][ks] = Au[(rr*8 + ks*4 + (lane>>4)) ^ (rr&7)];
  }
  const bf16x8* wf = (const bf16x8*)wl0f;
  for (int cb=0;cb<8;cb++){
    f32x4 acc[4][2];
    #pragma unroll
    for (int a_=0;a_<4;a_++)
    #pragma unroll
    for (int b_=0;b_<2;b_++) acc[a_][b_] = f32x4{0.f,0.f,0.f,0.f};
    #pragma unroll
    for (int ct=0;ct<2;ct++)
    #pragma unroll
    for (int ks=0;ks<2;ks++){
      bf16x8 b = wf[cb*512 + ((wcol*2+ct)*2+ks)*64 + lane];
      #pragma unroll
      for (int rt=0;rt<4;rt++) acc[rt][ct] = MFMA(a[rt][ks], b, acc[rt][ct]);
    }
    #pragma unroll
    for (int rt=0;rt<4;rt++)
    #pragma unroll
    for (int q=0;q<4;q++){
      long parent = row0 + wrow*64 + rt*16 + (lane>>4)*4 + q;
      if (parent < n){
        int m = inv[parent*8 + cb];
        if (m >= 0){
          #pragma unroll
          for (int ct=0;ct<2;ct++){
            int col = wcol*32 + ct*16 + (lane&15);
            tmpb[(long)m*64 + col] = f2b(acc[rt][ct][q] + bl0[cb*64+col]);
          }
        }
      }
    }
  }
}

// fused pred[1]: barrier-free conv (M rows) + prelu -> wave-private LDS q tile,
// then logits = q @ Wl1 + bl1, log_softmax + CE (no q / logits in HBM).
__global__ __launch_bounds__(256) void k_convloss(
    const short* __restrict__ xin, const int* __restrict__ nbr,
    const void* __restrict__ maskp, const short* __restrict__ wfrag,
    const float* __restrict__ bias, const float* __restrict__ alphap,
    const short* __restrict__ wl1f, const float* __restrict__ bl1,
    const void* __restrict__ bins0, float* __restrict__ ce_out,
    int n, const int* __restrict__ flagp)
{
  __shared__ bf16x8 Qu[1024];   // 4 waves x (32 rows x 8 units), XOR-swizzled
  int flag = *flagp;
  int t=threadIdx.x, lane=t&63, wid=t>>6;
  long wrow0 = (long)blockIdx.x*128 + wid*32;
  long rA0 = wrow0 + (lane&15), rA1 = rA0 + 16;
  bool vA0 = rA0 < n, vA1 = rA1 < n;
  int uoff = lane>>4;
  const bf16x8* wf = (const bf16x8*)wfrag;

  int nb_c0, nb_c1, nb_n0, nb_n1;
  bool m_c0, m_c1, m_n0, m_n1;
  bf16x8 an[2][2];
  const bf16x8 z = {0,0,0,0,0,0,0,0};

  nb_c0 = vA0 ? nbr[rA0*27+0] : 0;  m_c0 = vA0 && rd_mask(maskp, rA0*27+0, flag);
  nb_c1 = vA1 ? nbr[rA1*27+0] : 0;  m_c1 = vA1 && rd_mask(maskp, rA1*27+0, flag);
  {
    const bf16x8* s0 = (const bf16x8*)(xin + (long)nb_c0*64) + uoff;
    const bf16x8* s1 = (const bf16x8*)(xin + (long)nb_c1*64) + uoff;
    an[0][0] = m_c0 ? s0[0] : z;  an[0][1] = m_c0 ? s0[4] : z;
    an[1][0] = m_c1 ? s1[0] : z;  an[1][1] = m_c1 ? s1[4] : z;
  }
  nb_n0 = vA0 ? nbr[rA0*27+1] : 0;  m_n0 = vA0 && rd_mask(maskp, rA0*27+1, flag);
  nb_n1 = vA1 ? nbr[rA1*27+1] : 0;  m_n1 = vA1 && rd_mask(maskp, rA1*27+1, flag);

  f32x4 acc[2][4];
  #pragma unroll
  for (int a_=0;a_<2;a_++)
  #pragma unroll
  for (int b_=0;b_<4;b_++) acc[a_][b_] = f32x4{0.f,0.f,0.f,0.f};

  for (int k=0;k<27;k++){
    bf16x8 ac[2][2];
    ac[0][0]=an[0][0]; ac[0][1]=an[0][1]; ac[1][0]=an[1][0]; ac[1][1]=an[1][1];
    if (k<26){
      const bf16x8* s0 = (const bf16x8*)(xin + (long)nb_n0*64) + uoff;
      const bf16x8* s1 = (const bf16x8*)(xin + (long)nb_n1*64) + uoff;
      an[0][0] = m_n0 ? s0[0] : z;  an[0][1] = m_n0 ? s0[4] : z;
      an[1][0] = m_n1 ? s1[0] : z;  an[1][1] = m_n1 ? s1[4] : z;
      if (k<25){
        nb_n0 = vA0 ? nbr[rA0*27+k+2] : 0;  m_n0 = vA0 && rd_mask(maskp, rA0*27+k+2, flag);
        nb_n1 = vA1 ? nbr[rA1*27+k+2] : 0;  m_n1 = vA1 && rd_mask(maskp, rA1*27+k+2, flag);
      }
    }
    const bf16x8* wfk = wf + (long)k*512;
    #pragma unroll
    for (int ct=0;ct<4;ct++){
      bf16x8 b0 = wfk[(ct*2+0)*64 + lane];
      bf16x8 b1 = wfk[(ct*2+1)*64 + lane];
      acc[0][ct] = MFMA(ac[0][0], b0, acc[0][ct]);
      acc[1][ct] = MFMA(ac[1][0], b0, acc[1][ct]);
      acc[0][ct] = MFMA(ac[0][1], b1, acc[0][ct]);
      acc[1][ct] = MFMA(ac[1][1], b1, acc[1][ct]);
    }
  }
  // q = prelu(conv + bias) -> wave-private LDS tile (32 rows x 64 ch)
  float al = alphap[0];
  short* Qs = (short*)(Qu + wid*256);
  #pragma unroll
  for (int rt=0;rt<2;rt++)
  #pragma unroll
  for (int ct=0;ct<4;ct++){
    int col = ct*16 + (lane&15);
    float bc = bias[col];
    #pragma unroll
    for (int q=0;q<4;q++){
      int lrow = rt*16 + (lane>>4)*4 + q;
      float v = acc[rt][ct][q] + bc;
      v = v>=0.f ? v : al*v;
      Qs[(lrow*8 + ((col>>3)^(lrow&7)))*8 + (col&7)] = f2b(v);
    }
  }
  __syncthreads();
  // loss: per wave, 2 row-tiles of 16; B frags from global (L1-resident 32KB).
  const bf16x8* wl = (const bf16x8*)wl1f;
  const bf16x8* Qw = Qu + wid*256;
  float ce_local = 0.f;
  int c0=lane&15, gq=lane>>4;
  #pragma unroll
  for (int rt=0; rt<2; rt++){
    int rr = rt*16 + (lane&15);
    bf16x8 a0 = Qw[(rr*8 + (lane>>4)) ^ (rr&7)];
    bf16x8 a1 = Qw[(rr*8 + 4 + (lane>>4)) ^ (rr&7)];
    f32x4 acl[16];
    #pragma unroll
    for (int ct=0;ct<16;ct++) acl[ct]=f32x4{0.f,0.f,0.f,0.f};
    #pragma unroll
    for (int ct=0;ct<16;ct++){
      acl[ct]=MFMA(a0, wl[(ct*2)*64+lane],   acl[ct]);
      acl[ct]=MFMA(a1, wl[(ct*2+1)*64+lane], acl[ct]);
    }
    #pragma unroll
    for (int q=0;q<4;q++){
      long rowg = wrow0 + rt*16 + gq*4 + q;
      bool valid = rowg < (long)n;
      int oct=-1;
      if (valid){
        #pragma unroll
        for (int j=0;j<8;j++) if (rd_mask(bins0, rowg*8+j, flag)) oct += (1<<j);
      }
      float lg[16]; float mx=-3e38f;
      #pragma unroll
      for (int ct=0;ct<16;ct++){
        int col=ct*16+c0;
        float v = acl[ct][q] + ((col<255)? bl1[col] : -1e30f);
        lg[ct]=v; mx=fmaxf(mx,v);
      }
      #pragma unroll
      for (int d=1; d<16; d<<=1) mx = fmaxf(mx, __shfl_xor(mx,d));
      float sm=0.f, selv=0.f;
      #pragma unroll
      for (int ct=0;ct<16;ct++){
        sm += __expf(lg[ct]-mx);
        if (valid && ct==(oct>>4) && c0==(oct&15)) selv=lg[ct];
      }
      #pragma unroll
      for (int d=1; d<16; d<<=1) sm += __shfl_xor(sm,d);
      if (valid && c0==(oct&15)) ce_local += mx + __logf(sm) - selv;
    }
  }
  #pragma unroll
  for (int d=1; d<64; d<<=1) ce_local += __shfl_xor(ce_local,d);
  if (lane==0) atomicAdd(ce_out, ce_local);
}

__global__ void k_final(const float* __restrict__ ce, float* __restrict__ out, float scale){
  if (threadIdx.x==0 && blockIdx.x==0) out[0] = ce[0]*scale;
}

extern "C" void kernel_launch(void* const* d_in, const int* in_sizes, int n_in,
                              void* d_out, int out_size, void* d_ws, size_t ws_size,
                              hipStream_t stream) {
  const int N = in_sizes[0] / 64;      // 150000
  const int M = in_sizes[3];           // 600000
  char* ws = (char*)d_ws;
  int*   flag = (int*)ws;
  float* ce   = (float*)(ws + 64);
  short* wconvf = (short*)(ws + 256);          // 4 x 110592 shorts
  short* wb1f = wconvf;
  short* wb2f = wb1f + 110592;
  short* wp0f = wb2f + 110592;
  short* wp1f = wp0f + 110592;
  short* wdecf= wp1f + 110592;                 // 8192
  short* wl0f = wdecf + 8192;                  // 32768
  short* wl1f = wl0f + 32768;                  // 16384  -> ends < 1 MB
  int*   inv  = (int*)(ws + ((size_t)1<<20));  // N*8 ints (4.8 MB)
  size_t off_act = (((size_t)1<<20) + (size_t)N*8*4 + 4095) & ~(size_t)4095;
  short* xb   = (short*)(ws + off_act);        // [N,64] bf16 (19.2 MB)
  short* h1b  = xb + (size_t)N*64;
  short* recb = h1b + (size_t)N*64;            // inside tmpb span; dead before overwrite
  short* r0b  = xb;                            // alias: xb dead after conv2
  short* tmpb = h1b;                           // [M,64] bf16 (76.8 MB); h1b/recb dead
  // total ws footprint ~= off_act + 19.2MB + 76.8MB ~= 102 MB

  const float* a_dec = (const float*)d_in[11];
  int gN = (N+127)/128, gM = (M+127)/128;

  k_detect<<<1,64,0,stream>>>(d_in[5], flag, ce);
  k_prep<<<1952,256,0,stream>>>(
      (const float*)d_in[9], (const float*)d_in[12], (const float*)d_in[15],
      (const float*)d_in[18], (const float*)d_in[23], (const float*)d_in[21],
      (const float*)d_in[26], wdecf, wconvf, wl0f, wl1f);
  k_inv_init<<<(N*8+255)/256,256,0,stream>>>(inv, N*8);
  k_inv_fill<<<(M+255)/256,256,0,stream>>>((const int*)d_in[3], inv, M);
  k_dec<<<gN,256,0,stream>>>((const float*)d_in[0], (const float*)d_in[1], wdecf,
      (const float*)d_in[10], a_dec, xb, N);
  // block conv1
  k_conv<<<gN,256,0,stream>>>(xb, (const int*)d_in[4], d_in[5], wb1f,
      (const float*)d_in[13], (const float*)d_in[14], nullptr, h1b, nullptr, N, flag);
  // block conv2 + residual(x) -> rec (bf16 + f32 to d_out)
  k_conv<<<gN,256,0,stream>>>(h1b, (const int*)d_in[4], d_in[5], wb2f,
      (const float*)d_in[16], (const float*)d_in[17], xb, recb, (float*)d_out, N, flag);
  // pred[0] conv -> r0 (into xb slot)
  k_conv<<<gN,256,0,stream>>>(recb, (const int*)d_in[4], d_in[5], wp0f,
      (const float*)d_in[19], (const float*)d_in[20], nullptr, r0b, nullptr, N, flag);
  // fused Linear(64->512) + child scatter -> tmp[M,64]
  k_linscatter<<<gN,256,0,stream>>>(r0b, wl0f, (const float*)d_in[22], inv, tmpb, N);
  // fused pred[1] conv + Wl1 + log_softmax + CE
  k_convloss<<<gM,256,0,stream>>>(tmpb, (const int*)d_in[6], d_in[7], wp1f,
      (const float*)d_in[24], (const float*)d_in[25], wl1f, (const float*)d_in[27],
      d_in[2], ce, M, flag);
  float scale = 1.4426950408889634f / (float)M;
  k_final<<<1,64,0,stream>>>(ce, (float*)d_out + (size_t)N*64, scale);
}

// Round 4
// 1142.485 us; speedup vs baseline: 1.8733x; 1.8733x over previous
//
#include <hip/hip_runtime.h>
#include <hip/hip_bf16.h>

typedef __attribute__((ext_vector_type(8))) short bf16x8;
typedef __attribute__((ext_vector_type(4))) float f32x4;

#define MFMA(a,b,c) __builtin_amdgcn_mfma_f32_16x16x32_bf16(a,b,c,0,0,0)

__device__ __forceinline__ short f2b(float v){
  __hip_bfloat16 b = __float2bfloat16(v);
  return *reinterpret_cast<short*>(&b);
}
__device__ __forceinline__ float b2f(short s){
  __hip_bfloat16 b;
  *reinterpret_cast<short*>(&b) = s;
  return __bfloat162float(b);
}
// bool arrays may arrive as uint8 / int32 / float32 depending on harness upload.
__device__ __forceinline__ bool rd_mask(const void* m, long i, int flag){
  if (flag==1) return ((const int*)m)[i] != 0;
  if (flag==2) return ((const float*)m)[i] != 0.0f;
  return ((const unsigned char*)m)[i] != 0;
}

// async global->LDS, 16B per lane; LDS dest = wave-uniform base + lane*16.
__device__ __forceinline__ void gld16(const void* g, void* l){
  __builtin_amdgcn_global_load_lds(
      (const __attribute__((address_space(1))) unsigned int*)g,
      (__attribute__((address_space(3))) unsigned int*)l, 16, 0, 0);
}

// detect bool-array storage; mask0[i][13] (center tap) is always true.
// also zero the 128B zero-row and the CE accumulator.
__global__ void k_detect(const void* __restrict__ mask, int* flag, float* ce,
                         int* zrow){
  int t = threadIdx.x;
  if (t < 32 && blockIdx.x==0) zrow[t] = 0;
  if (t==0 && blockIdx.x==0){
    const int* mi = (const int*)mask;
    const float* mf = (const float*)mask;
    bool all_i=true, all_f=true;
    for (int i=0;i<100;i++){
      if (mi[i*27+13] != 1) all_i=false;
      if (mf[i*27+13] != 1.0f) all_f=false;
    }
    *flag = all_i ? 1 : (all_f ? 2 : 0);
    *ce = 0.0f;
  }
}

// Pack all weights (f32) into bf16 MFMA B-fragment layout.
// conv frags: [k][ct4][ks2][lane64][e8]; dec: [ks4][ct4][lane][e] (cin padded 72->128);
// wl0: [cb8][ct4][ks2][lane][e]; wl1: [ct16][ks2][lane][e] (col 255 zero-padded).
__global__ __launch_bounds__(256) void k_prep(
    const float* __restrict__ Wdec, const float* __restrict__ Wb1,
    const float* __restrict__ Wb2, const float* __restrict__ Wp0,
    const float* __restrict__ Wp1, const float* __restrict__ Wl0,
    const float* __restrict__ Wl1,
    short* __restrict__ wdecf, short* __restrict__ wconvf,
    short* __restrict__ wl0f, short* __restrict__ wl1f)
{
  int i = blockIdx.x*256 + threadIdx.x;
  if (i < 442368){
    int ci = i / 110592, r = i % 110592;
    int e = r&7, ln=(r>>3)&63, ks=(r>>9)&1, ct=(r>>10)&3, k=r>>12;
    int cin = ks*32 + (ln>>4)*8 + e, cout = ct*16 + (ln&15);
    const float* W = ci==0?Wb1: ci==1?Wb2: ci==2?Wp0:Wp1;
    wconvf[i] = f2b(W[(k*64+cin)*64 + cout]);
  } else if (i < 450560){
    int r = i - 442368;
    int e=r&7, ln=(r>>3)&63, ct=(r>>9)&3, ks=(r>>11)&3;
    int cin = ks*32 + (ln>>4)*8 + e, cout = ct*16 + (ln&15);
    wdecf[r] = f2b(cin<72 ? Wdec[cin*64+cout] : 0.f);
  } else if (i < 483328){
    int r = i - 450560;
    int e=r&7, ln=(r>>3)&63, ks=(r>>9)&1, ct=(r>>10)&3, cb=(r>>12)&7;
    int cin = ks*32+(ln>>4)*8+e, col = cb*64+ct*16+(ln&15);
    wl0f[r] = f2b(Wl0[cin*512 + col]);
  } else if (i < 499712){
    int r = i - 483328;
    int e=r&7, ln=(r>>3)&63, ks=(r>>9)&1, ct=(r>>10)&15;
    int cin = ks*32+(ln>>4)*8+e, col = ct*16+(ln&15);
    wl1f[r] = f2b(col<255 ? Wl1[cin*255+col] : 0.f);
  }
}

__global__ void k_inv_init(int* __restrict__ inv, int total){
  int i = blockIdx.x*256 + threadIdx.x;
  if (i < total) inv[i] = -1;
}
__global__ void k_inv_fill(const int* __restrict__ sel, int* __restrict__ inv, int M_){
  int m = blockIdx.x*256 + threadIdx.x;
  if (m < M_) inv[sel[m]] = m;
}

// dec: x = prelu(concat(cur_rec_F, bins1_f) @ Wdec + b, a) ; K padded 72->128
__global__ __launch_bounds__(256) void k_dec(
    const float* __restrict__ xf, const float* __restrict__ bf1,
    const short* __restrict__ wfrag, const float* __restrict__ bias,
    const float* __restrict__ alphap, short* __restrict__ outb, int n)
{
  __shared__ bf16x8 Au[2048];  // 128 rows x 16 units, XOR-swizzled
  int t=threadIdx.x, lane=t&63, wid=t>>6;
  long row0 = (long)blockIdx.x*128;
  int sr=t>>1, sh=t&1;
  long r = row0+sr;
  bf16x8 u[8];
  #pragma unroll
  for (int j=0;j<8;j++) u[j] = bf16x8{0,0,0,0,0,0,0,0};
  if (r<n){
    if (sh==0){
      const f32x4* s = (const f32x4*)(xf + r*64);
      #pragma unroll
      for (int j=0;j<8;j++){
        f32x4 v0 = s[2*j], v1 = s[2*j+1];
        bf16x8 b;
        b[0]=f2b(v0[0]); b[1]=f2b(v0[1]); b[2]=f2b(v0[2]); b[3]=f2b(v0[3]);
        b[4]=f2b(v1[0]); b[5]=f2b(v1[1]); b[6]=f2b(v1[2]); b[7]=f2b(v1[3]);
        u[j]=b;
      }
    } else {
      const float* s = bf1 + r*8;
      bf16x8 b;
      #pragma unroll
      for (int j=0;j<8;j++) b[j]=f2b(s[j]);
      u[0]=b;
    }
  }
  int ub = sr*16 + sh*8;
  #pragma unroll
  for (int j=0;j<8;j++) Au[(ub+j)^(sr&7)] = u[j];
  __syncthreads();
  const bf16x8* wf = (const bf16x8*)wfrag;
  f32x4 acc[2][4];
  #pragma unroll
  for (int a_=0;a_<2;a_++)
  #pragma unroll
  for (int b_=0;b_<4;b_++) acc[a_][b_] = f32x4{0.f,0.f,0.f,0.f};
  #pragma unroll
  for (int ks=0;ks<4;ks++){
    bf16x8 a[2];
    #pragma unroll
    for (int rt=0;rt<2;rt++){
      int rr = wid*32 + rt*16 + (lane&15);
      a[rt] = Au[(rr*16 + ks*4 + (lane>>4)) ^ (rr&7)];
    }
    #pragma unroll
    for (int ct=0;ct<4;ct++){
      bf16x8 b = wf[(ks*4 + ct)*64 + lane];
      #pragma unroll
      for (int rt=0;rt<2;rt++) acc[rt][ct] = MFMA(a[rt], b, acc[rt][ct]);
    }
  }
  float al = alphap[0];
  #pragma unroll
  for (int rt=0;rt<2;rt++)
  #pragma unroll
  for (int ct=0;ct<4;ct++){
    int col = ct*16+(lane&15);
    float bc = bias[col];
    #pragma unroll
    for (int q=0;q<4;q++){
      long rr = row0 + wid*32 + rt*16 + (lane>>4)*4 + q;
      if (rr<n){
        float v = acc[rt][ct][q] + bc;
        v = v>=0.f? v : al*v;
        outb[rr*64+col] = f2b(v);
      }
    }
  }
}

// ---------------------------------------------------------------------------
// Sparse-conv core, T3/T4 style: per wave 32 rows x 64 cols. Per tap, 4 async
// global_load_lds gather the wave's 32 rows (seg-XOR-swizzled via pre-swizzled
// per-lane global source), 2 more stage the wave's quarter of the 8KB weight
// tile into a block-shared LDS ring. Depth-2 pipeline, counted vmcnt(6)
// (never 0 mid-loop), raw s_barriers (no compiler drain), masked taps
// redirected to a zeroed 128B row. nbr+mask packed into LDS up front so the
// tap loop's vmem FIFO contains ONLY the 6 counted ops per tap.
// ---------------------------------------------------------------------------
__device__ __forceinline__ void conv_core(
    const short* __restrict__ xin, const int* __restrict__ nbr,
    const void* __restrict__ maskp, int flag,
    const short* __restrict__ wfrag, const short* __restrict__ zrow,
    short* As_, short* Bs_, int* nbrS_,
    int n, int lane, int wid, long wrow0, f32x4 acc[2][4])
{
  int* nbrW = nbrS_ + wid*864;
  {
    long base = wrow0*27;
    #pragma unroll
    for (int tt=0; tt<14; tt++){
      int idx = tt*64 + lane;
      if (idx < 864){
        int pk = -1;
        long row = wrow0 + idx/27;
        if (row < (long)n){
          long gi = base + idx;
          int nb = nbr[gi];
          if (rd_mask(maskp, gi, flag)) pk = nb;
        }
        nbrW[idx] = pk;
      }
    }
  }
  auto issueA = [&](int t, const int p[4]){
    short* dst = As_ + (wid*2 + (t&1))*2048;
    #pragma unroll
    for (int j=0;j<4;j++){
      int r = j*8 + (lane>>3);
      int s = (lane&7) ^ (r&7);              // pre-swizzled global source
      const short* src = (p[j]<0) ? (zrow + s*8) : (xin + (long)p[j]*64 + s*8);
      gld16(src, dst + j*512);
    }
  };
  auto issueB = [&](int t){
    short* dst = Bs_ + (t&1)*4096 + wid*1024;
    #pragma unroll
    for (int j=0;j<2;j++){
      const short* src = wfrag + ((long)t*512 + wid*128 + j*64 + lane)*8;
      gld16(src, dst + j*512);
    }
  };
  auto readN = [&](int t, int p[4]){
    #pragma unroll
    for (int j=0;j<4;j++) p[j] = nbrW[(j*8 + (lane>>3))*27 + t];
  };
  int p0[4], p1[4];
  readN(0, p0); readN(1, p1);
  issueA(0, p0); issueB(0); issueA(1, p1); issueB(1);
  #pragma unroll
  for (int k=0;k<27;k++){
    int pn[4];
    if (k < 25) readN(k+2, pn);
    if (k < 26) { asm volatile("s_waitcnt vmcnt(6)" ::: "memory"); }
    else        { asm volatile("s_waitcnt vmcnt(0)" ::: "memory"); }
    __builtin_amdgcn_sched_barrier(0);
    __builtin_amdgcn_s_barrier();            // all waves' tap-k shares landed
    bf16x8 a[2][2], b[4][2];
    const bf16x8* Aw = (const bf16x8*)(As_ + (wid*2 + (k&1))*2048);
    #pragma unroll
    for (int rt=0;rt<2;rt++){
      int r = rt*16 + (lane&15);
      #pragma unroll
      for (int h=0;h<2;h++)
        a[rt][h] = Aw[(r*8 + h*4 + (lane>>4)) ^ (r&7)];
    }
    const bf16x8* Bw = (const bf16x8*)(Bs_ + (k&1)*4096);
    #pragma unroll
    for (int ct=0;ct<4;ct++)
    #pragma unroll
    for (int h=0;h<2;h++)
      b[ct][h] = Bw[(ct*2+h)*64 + lane];
    asm volatile("s_waitcnt lgkmcnt(0)" ::: "memory");   // frags in regs
    __builtin_amdgcn_sched_barrier(0);
    __builtin_amdgcn_s_barrier();            // all waves done reading slot k&1
    if (k < 25) { issueA(k+2, pn); issueB(k+2); }
    #pragma unroll
    for (int ct=0;ct<4;ct++)
    #pragma unroll
    for (int h=0;h<2;h++){
      acc[0][ct] = MFMA(a[0][h], b[ct][h], acc[0][ct]);
      acc[1][ct] = MFMA(a[1][h], b[ct][h], acc[1][ct]);
    }
  }
}

// sparse conv: y[i] = sum_k mask[i,k]*x[nbr[i,k]] @ W[k] + b  (+resid) -> prelu
__global__ __launch_bounds__(256,2) void k_conv(
    const short* __restrict__ xin, const int* __restrict__ nbr,
    const void* __restrict__ maskp, const short* __restrict__ wfrag,
    const float* __restrict__ bias, const float* __restrict__ alphap,
    const short* __restrict__ resid, short* __restrict__ outb,
    float* __restrict__ outf, int n, const int* __restrict__ flagp,
    const short* __restrict__ zrow)
{
  __shared__ __align__(16) short As_[16384];   // 4 waves x 2 slots x 4KB
  __shared__ __align__(16) short Bs_[8192];    // 2 slots x 8KB (block-shared)
  __shared__ int nbrS_[3456];                  // 4 waves x 32 rows x 27
  int flag = *flagp;
  int t=threadIdx.x, lane=t&63, wid=t>>6;
  long wrow0 = (long)blockIdx.x*128 + wid*32;
  f32x4 acc[2][4];
  #pragma unroll
  for (int a_=0;a_<2;a_++)
  #pragma unroll
  for (int b_=0;b_<4;b_++) acc[a_][b_] = f32x4{0.f,0.f,0.f,0.f};
  conv_core(xin, nbr, maskp, flag, wfrag, zrow, As_, Bs_, nbrS_,
            n, lane, wid, wrow0, acc);
  float al = alphap ? alphap[0] : 0.f;
  #pragma unroll
  for (int rt=0;rt<2;rt++)
  #pragma unroll
  for (int ct=0;ct<4;ct++){
    int col = ct*16 + (lane&15);
    float bc = bias[col];
    #pragma unroll
    for (int q=0;q<4;q++){
      long rr = wrow0 + rt*16 + (lane>>4)*4 + q;
      if (rr < n){
        float v = acc[rt][ct][q] + bc;
        if (resid) v += b2f(resid[rr*64+col]);
        if (alphap) v = v>=0.f ? v : al*v;
        outb[rr*64+col] = f2b(v);
        if (outf) outf[rr*64+col] = v;
      }
    }
  }
}

// fused p = r0 @ Wl0 + bl0 (64->512) + child-gather scatter to tmp[M,64].
__global__ __launch_bounds__(256) void k_linscatter(
    const short* __restrict__ r0b, const short* __restrict__ wl0f,
    const float* __restrict__ bl0, const int* __restrict__ inv,
    short* __restrict__ tmpb, int n)
{
  __shared__ bf16x8 Au[1024];
  int t=threadIdx.x, lane=t&63, wid=t>>6, wrow=wid>>1, wcol=wid&1;
  long row0=(long)blockIdx.x*128;
  int sr=t>>1, sh=t&1;
  long r=row0+sr;
  bf16x8 z = {0,0,0,0,0,0,0,0};
  const bf16x8* s = (const bf16x8*)(r0b + r*64 + sh*32);
  int ub = sr*8+sh*4;
  #pragma unroll
  for (int j=0;j<4;j++) Au[(ub+j)^(sr&7)] = (r<n)? s[j] : z;
  __syncthreads();
  bf16x8 a[4][2];
  #pragma unroll
  for (int rt=0;rt<4;rt++){
    int rr = wrow*64 + rt*16 + (lane&15);
    #pragma unroll
    for (int ks=0;ks<2;ks++)
      a[rt][ks] = Au[(rr*8 + ks*4 + (lane>>4)) ^ (rr&7)];
  }
  const bf16x8* wf = (const bf16x8*)wl0f;
  for (int cb=0;cb<8;cb++){
    f32x4 acc[4][2];
    #pragma unroll
    for (int a_=0;a_<4;a_++)
    #pragma unroll
    for (int b_=0;b_<2;b_++) acc[a_][b_] = f32x4{0.f,0.f,0.f,0.f};
    #pragma unroll
    for (int ct=0;ct<2;ct++)
    #pragma unroll
    for (int ks=0;ks<2;ks++){
      bf16x8 b = wf[cb*512 + ((wcol*2+ct)*2+ks)*64 + lane];
      #pragma unroll
      for (int rt=0;rt<4;rt++) acc[rt][ct] = MFMA(a[rt][ks], b, acc[rt][ct]);
    }
    #pragma unroll
    for (int rt=0;rt<4;rt++)
    #pragma unroll
    for (int q=0;q<4;q++){
      long parent = row0 + wrow*64 + rt*16 + (lane>>4)*4 + q;
      if (parent < n){
        int m = inv[parent*8 + cb];
        if (m >= 0){
          #pragma unroll
          for (int ct=0;ct<2;ct++){
            int col = wcol*32 + ct*16 + (lane&15);
            tmpb[(long)m*64 + col] = f2b(acc[rt][ct][q] + bl0[cb*64+col]);
          }
        }
      }
    }
  }
}

// fused pred[1]: pipelined conv (M rows) + prelu -> wave-private LDS q tile,
// then logits = q @ Wl1 + bl1, log_softmax + CE (no q / logits in HBM).
__global__ __launch_bounds__(256,2) void k_convloss(
    const short* __restrict__ xin, const int* __restrict__ nbr,
    const void* __restrict__ maskp, const short* __restrict__ wfrag,
    const float* __restrict__ bias, const float* __restrict__ alphap,
    const short* __restrict__ wl1f, const float* __restrict__ bl1,
    const void* __restrict__ bins0, float* __restrict__ ce_out,
    int n, const int* __restrict__ flagp, const short* __restrict__ zrow)
{
  __shared__ __align__(16) short As_[16384];
  __shared__ __align__(16) short Bs_[8192];
  __shared__ int nbrS_[3456];
  int flag = *flagp;
  int t=threadIdx.x, lane=t&63, wid=t>>6;
  long wrow0 = (long)blockIdx.x*128 + wid*32;
  f32x4 acc[2][4];
  #pragma unroll
  for (int a_=0;a_<2;a_++)
  #pragma unroll
  for (int b_=0;b_<4;b_++) acc[a_][b_] = f32x4{0.f,0.f,0.f,0.f};
  conv_core(xin, nbr, maskp, flag, wfrag, zrow, As_, Bs_, nbrS_,
            n, lane, wid, wrow0, acc);
  // q = prelu(conv + bias) -> wave-private LDS tile (reuse wave's slot 0;
  // all pipeline glds drained by the final vmcnt(0)).
  float al = alphap[0];
  short* Qs = As_ + (wid*2)*2048;
  #pragma unroll
  for (int rt=0;rt<2;rt++)
  #pragma unroll
  for (int ct=0;ct<4;ct++){
    int col = ct*16 + (lane&15);
    float bc = bias[col];
    #pragma unroll
    for (int q=0;q<4;q++){
      int lrow = rt*16 + (lane>>4)*4 + q;
      float v = acc[rt][ct][q] + bc;
      v = v>=0.f ? v : al*v;
      Qs[(lrow*8 + ((col>>3)^(lrow&7)))*8 + (col&7)] = f2b(v);
    }
  }
  // loss: per wave, 2 row-tiles of 16; wl1 frags from global (L2-resident).
  const bf16x8* wl = (const bf16x8*)wl1f;
  const bf16x8* Qw = (const bf16x8*)Qs;
  float ce_local = 0.f;
  int c0=lane&15, gq=lane>>4;
  #pragma unroll
  for (int rt=0; rt<2; rt++){
    int rr = rt*16 + (lane&15);
    bf16x8 a0 = Qw[(rr*8 + (lane>>4)) ^ (rr&7)];
    bf16x8 a1 = Qw[(rr*8 + 4 + (lane>>4)) ^ (rr&7)];
    f32x4 acl[16];
    #pragma unroll
    for (int ct=0;ct<16;ct++) acl[ct]=f32x4{0.f,0.f,0.f,0.f};
    #pragma unroll
    for (int ct=0;ct<16;ct++){
      acl[ct]=MFMA(a0, wl[(ct*2)*64+lane],   acl[ct]);
      acl[ct]=MFMA(a1, wl[(ct*2+1)*64+lane], acl[ct]);
    }
    #pragma unroll
    for (int q=0;q<4;q++){
      long rowg = wrow0 + rt*16 + gq*4 + q;
      bool valid = rowg < (long)n;
      int oct=-1;
      if (valid){
        #pragma unroll
        for (int j=0;j<8;j++) if (rd_mask(bins0, rowg*8+j, flag)) oct += (1<<j);
      }
      float lg[16]; float mx=-3e38f;
      #pragma unroll
      for (int ct=0;ct<16;ct++){
        int col=ct*16+c0;
        float v = acl[ct][q] + ((col<255)? bl1[col] : -1e30f);
        lg[ct]=v; mx=fmaxf(mx,v);
      }
      #pragma unroll
      for (int d=1; d<16; d<<=1) mx = fmaxf(mx, __shfl_xor(mx,d));
      float sm=0.f, selv=0.f;
      #pragma unroll
      for (int ct=0;ct<16;ct++){
        sm += __expf(lg[ct]-mx);
        if (valid && ct==(oct>>4) && c0==(oct&15)) selv=lg[ct];
      }
      #pragma unroll
      for (int d=1; d<16; d<<=1) sm += __shfl_xor(sm,d);
      if (valid && c0==(oct&15)) ce_local += mx + __logf(sm) - selv;
    }
  }
  #pragma unroll
  for (int d=1; d<64; d<<=1) ce_local += __shfl_xor(ce_local,d);
  if (lane==0) atomicAdd(ce_out, ce_local);
}

__global__ void k_final(const float* __restrict__ ce, float* __restrict__ out, float scale){
  if (threadIdx.x==0 && blockIdx.x==0) out[0] = ce[0]*scale;
}

extern "C" void kernel_launch(void* const* d_in, const int* in_sizes, int n_in,
                              void* d_out, int out_size, void* d_ws, size_t ws_size,
                              hipStream_t stream) {
  const int N = in_sizes[0] / 64;      // 150000
  const int M = in_sizes[3];           // 600000
  char* ws = (char*)d_ws;
  int*   flag = (int*)ws;
  float* ce   = (float*)(ws + 64);
  short* zrow = (short*)(ws + 128);            // 128B zero row
  short* wconvf = (short*)(ws + 256);          // 4 x 110592 shorts
  short* wb1f = wconvf;
  short* wb2f = wb1f + 110592;
  short* wp0f = wb2f + 110592;
  short* wp1f = wp0f + 110592;
  short* wdecf= wp1f + 110592;                 // 8192
  short* wl0f = wdecf + 8192;                  // 32768
  short* wl1f = wl0f + 32768;                  // 16384  -> ends < 1 MB
  int*   inv  = (int*)(ws + ((size_t)1<<20));  // N*8 ints (4.8 MB)
  size_t off_act = (((size_t)1<<20) + (size_t)N*8*4 + 4095) & ~(size_t)4095;
  short* xb   = (short*)(ws + off_act);        // [N,64] bf16 (19.2 MB)
  short* h1b  = xb + (size_t)N*64;
  short* recb = h1b + (size_t)N*64;            // inside tmpb span; dead before overwrite
  short* r0b  = xb;                            // alias: xb dead after conv2
  short* tmpb = h1b;                           // [M,64] bf16 (76.8 MB); h1b/recb dead
  // total ws footprint ~= off_act + 19.2MB + 76.8MB ~= 102 MB

  const float* a_dec = (const float*)d_in[11];
  int gN = (N+127)/128, gM = (M+127)/128;

  k_detect<<<1,64,0,stream>>>(d_in[5], flag, ce, (int*)zrow);
  k_prep<<<1952,256,0,stream>>>(
      (const float*)d_in[9], (const float*)d_in[12], (const float*)d_in[15],
      (const float*)d_in[18], (const float*)d_in[23], (const float*)d_in[21],
      (const float*)d_in[26], wdecf, wconvf, wl0f, wl1f);
  k_inv_init<<<(N*8+255)/256,256,0,stream>>>(inv, N*8);
  k_inv_fill<<<(M+255)/256,256,0,stream>>>((const int*)d_in[3], inv, M);
  k_dec<<<gN,256,0,stream>>>((const float*)d_in[0], (const float*)d_in[1], wdecf,
      (const float*)d_in[10], a_dec, xb, N);
  // block conv1
  k_conv<<<gN,256,0,stream>>>(xb, (const int*)d_in[4], d_in[5], wb1f,
      (const float*)d_in[13], (const float*)d_in[14], nullptr, h1b, nullptr, N, flag, zrow);
  // block conv2 + residual(x) -> rec (bf16 + f32 to d_out)
  k_conv<<<gN,256,0,stream>>>(h1b, (const int*)d_in[4], d_in[5], wb2f,
      (const float*)d_in[16], (const float*)d_in[17], xb, recb, (float*)d_out, N, flag, zrow);
  // pred[0] conv -> r0 (into xb slot)
  k_conv<<<gN,256,0,stream>>>(recb, (const int*)d_in[4], d_in[5], wp0f,
      (const float*)d_in[19], (const float*)d_in[20], nullptr, r0b, nullptr, N, flag, zrow);
  // fused Linear(64->512) + child scatter -> tmp[M,64]
  k_linscatter<<<gN,256,0,stream>>>(r0b, wl0f, (const float*)d_in[22], inv, tmpb, N);
  // fused pred[1] conv + Wl1 + log_softmax + CE
  k_convloss<<<gM,256,0,stream>>>(tmpb, (const int*)d_in[6], d_in[7], wp1f,
      (const float*)d_in[24], (const float*)d_in[25], wl1f, (const float*)d_in[27],
      d_in[2], ce, M, flag, zrow);
  float scale = 1.4426950408889634f / (float)M;
  k_final<<<1,64,0,stream>>>(ce, (float*)d_out + (size_t)N*64, scale);
}

// Round 7
// 1076.203 us; speedup vs baseline: 1.9886x; 1.0616x over previous
//
#include <hip/hip_runtime.h>
#include <hip/hip_bf16.h>

typedef __attribute__((ext_vector_type(8))) short bf16x8;
typedef __attribute__((ext_vector_type(4))) float f32x4;

#define MFMA(a,b,c) __builtin_amdgcn_mfma_f32_16x16x32_bf16(a,b,c,0,0,0)

__device__ __forceinline__ short f2b(float v){
  __hip_bfloat16 b = __float2bfloat16(v);
  return *reinterpret_cast<short*>(&b);
}
__device__ __forceinline__ float b2f(short s){
  __hip_bfloat16 b;
  *reinterpret_cast<short*>(&b) = s;
  return __bfloat162float(b);
}
// bool arrays may arrive as uint8 / int32 / float32 depending on harness upload.
__device__ __forceinline__ bool rd_mask(const void* m, long i, int flag){
  if (flag==1) return ((const int*)m)[i] != 0;
  if (flag==2) return ((const float*)m)[i] != 0.0f;
  return ((const unsigned char*)m)[i] != 0;
}

// async global->LDS; LDS dest = wave-uniform base + lane*size.
__device__ __forceinline__ void gld16(const void* g, void* l){
  __builtin_amdgcn_global_load_lds(
      (const __attribute__((address_space(1))) unsigned int*)g,
      (__attribute__((address_space(3))) unsigned int*)l, 16, 0, 0);
}
__device__ __forceinline__ void gld4(const void* g, void* l){
  __builtin_amdgcn_global_load_lds(
      (const __attribute__((address_space(1))) unsigned int*)g,
      (__attribute__((address_space(3))) unsigned int*)l, 4, 0, 0);
}

// detect bool-array storage; mask0[i][13] (center tap) is always true.
// also zero the 128B zero-row and the CE accumulator.
__global__ void k_detect(const void* __restrict__ mask, int* flag, float* ce,
                         int* zrow){
  int t = threadIdx.x;
  if (t < 32 && blockIdx.x==0) zrow[t] = 0;
  if (t==0 && blockIdx.x==0){
    const int* mi = (const int*)mask;
    const float* mf = (const float*)mask;
    bool all_i=true, all_f=true;
    for (int i=0;i<100;i++){
      if (mi[i*27+13] != 1) all_i=false;
      if (mf[i*27+13] != 1.0f) all_f=false;
    }
    *flag = all_i ? 1 : (all_f ? 2 : 0);
    *ce = 0.0f;
  }
}

// merge mask into nbr IN-PLACE: nbr[i] = mask[i] ? nbr[i] : -1.
// Idempotent; harness restores d_in before every timed launch.
__global__ __launch_bounds__(256) void k_merge(int* __restrict__ nbr,
    const void* __restrict__ mask, int total, const int* __restrict__ flagp){
  int flag = *flagp;
  int i = blockIdx.x*256 + threadIdx.x;
  if (i < total && !rd_mask(mask, i, flag)) nbr[i] = -1;
}

// Pack all weights (f32) into bf16 MFMA B-fragment layout.
// conv frags: [k][ct4][ks2][lane64][e8]; dec: [ks4][ct4][lane][e] (cin padded 72->128);
// wl0: [cb8][ct4][ks2][lane][e]; wl1: [ct16][ks2][lane][e] (col 255 zero-padded).
__global__ __launch_bounds__(256) void k_prep(
    const float* __restrict__ Wdec, const float* __restrict__ Wb1,
    const float* __restrict__ Wb2, const float* __restrict__ Wp0,
    const float* __restrict__ Wp1, const float* __restrict__ Wl0,
    const float* __restrict__ Wl1,
    short* __restrict__ wdecf, short* __restrict__ wconvf,
    short* __restrict__ wl0f, short* __restrict__ wl1f)
{
  int i = blockIdx.x*256 + threadIdx.x;
  if (i < 442368){
    int ci = i / 110592, r = i % 110592;
    int e = r&7, ln=(r>>3)&63, ks=(r>>9)&1, ct=(r>>10)&3, k=r>>12;
    int cin = ks*32 + (ln>>4)*8 + e, cout = ct*16 + (ln&15);
    const float* W = ci==0?Wb1: ci==1?Wb2: ci==2?Wp0:Wp1;
    wconvf[i] = f2b(W[(k*64+cin)*64 + cout]);
  } else if (i < 450560){
    int r = i - 442368;
    int e=r&7, ln=(r>>3)&63, ct=(r>>9)&3, ks=(r>>11)&3;
    int cin = ks*32 + (ln>>4)*8 + e, cout = ct*16 + (ln&15);
    wdecf[r] = f2b(cin<72 ? Wdec[cin*64+cout] : 0.f);
  } else if (i < 483328){
    int r = i - 450560;
    int e=r&7, ln=(r>>3)&63, ks=(r>>9)&1, ct=(r>>10)&3, cb=(r>>12)&7;
    int cin = ks*32+(ln>>4)*8+e, col = cb*64+ct*16+(ln&15);
    wl0f[r] = f2b(Wl0[cin*512 + col]);
  } else if (i < 499712){
    int r = i - 483328;
    int e=r&7, ln=(r>>3)&63, ks=(r>>9)&1, ct=(r>>10)&15;
    int cin = ks*32+(ln>>4)*8+e, col = ct*16+(ln&15);
    wl1f[r] = f2b(col<255 ? Wl1[cin*255+col] : 0.f);
  }
}

__global__ void k_inv_init(int* __restrict__ inv, int total){
  int i = blockIdx.x*256 + threadIdx.x;
  if (i < total) inv[i] = -1;
}
__global__ void k_inv_fill(const int* __restrict__ sel, int* __restrict__ inv, int M_){
  int m = blockIdx.x*256 + threadIdx.x;
  if (m < M_) inv[sel[m]] = m;
}

// dec: x = prelu(concat(cur_rec_F, bins1_f) @ Wdec + b, a) ; K padded 72->128
__global__ __launch_bounds__(256) void k_dec(
    const float* __restrict__ xf, const float* __restrict__ bf1,
    const short* __restrict__ wfrag, const float* __restrict__ bias,
    const float* __restrict__ alphap, short* __restrict__ outb, int n)
{
  __shared__ bf16x8 Au[2048];  // 128 rows x 16 units, XOR-swizzled
  int t=threadIdx.x, lane=t&63, wid=t>>6;
  long row0 = (long)blockIdx.x*128;
  int sr=t>>1, sh=t&1;
  long r = row0+sr;
  bf16x8 u[8];
  #pragma unroll
  for (int j=0;j<8;j++) u[j] = bf16x8{0,0,0,0,0,0,0,0};
  if (r<n){
    if (sh==0){
      const f32x4* s = (const f32x4*)(xf + r*64);
      #pragma unroll
      for (int j=0;j<8;j++){
        f32x4 v0 = s[2*j], v1 = s[2*j+1];
        bf16x8 b;
        b[0]=f2b(v0[0]); b[1]=f2b(v0[1]); b[2]=f2b(v0[2]); b[3]=f2b(v0[3]);
        b[4]=f2b(v1[0]); b[5]=f2b(v1[1]); b[6]=f2b(v1[2]); b[7]=f2b(v1[3]);
        u[j]=b;
      }
    } else {
      const float* s = bf1 + r*8;
      bf16x8 b;
      #pragma unroll
      for (int j=0;j<8;j++) b[j]=f2b(s[j]);
      u[0]=b;
    }
  }
  int ub = sr*16 + sh*8;
  #pragma unroll
  for (int j=0;j<8;j++) Au[(ub+j)^(sr&7)] = u[j];
  __syncthreads();
  const bf16x8* wf = (const bf16x8*)wfrag;
  f32x4 acc[2][4];
  #pragma unroll
  for (int a_=0;a_<2;a_++)
  #pragma unroll
  for (int b_=0;b_<4;b_++) acc[a_][b_] = f32x4{0.f,0.f,0.f,0.f};
  #pragma unroll
  for (int ks=0;ks<4;ks++){
    bf16x8 a[2];
    #pragma unroll
    for (int rt=0;rt<2;rt++){
      int rr = wid*32 + rt*16 + (lane&15);
      a[rt] = Au[(rr*16 + ks*4 + (lane>>4)) ^ (rr&7)];
    }
    #pragma unroll
    for (int ct=0;ct<4;ct++){
      bf16x8 b = wf[(ks*4 + ct)*64 + lane];
      #pragma unroll
      for (int rt=0;rt<2;rt++) acc[rt][ct] = MFMA(a[rt], b, acc[rt][ct]);
    }
  }
  float al = alphap[0];
  #pragma unroll
  for (int rt=0;rt<2;rt++)
  #pragma unroll
  for (int ct=0;ct<4;ct++){
    int col = ct*16+(lane&15);
    float bc = bias[col];
    #pragma unroll
    for (int q=0;q<4;q++){
      long rr = row0 + wid*32 + rt*16 + (lane>>4)*4 + q;
      if (rr<n){
        float v = acc[rt][ct][q] + bc;
        v = v>=0.f? v : al*v;
        outb[rr*64+col] = f2b(v);
      }
    }
  }
}

// ---------------------------------------------------------------------------
// Sparse-conv core v2. Per wave 32 rows x 64 cols. Counted-vmcnt gld pipeline:
// per tap: A 4 glds (gather, depth-2), B 2 glds (double-buffered 8KB tile,
// depth-1), N 1 gld (nbr window, 4-slot ring, depth-2). ONE barrier per tap
// (publishes B; everything else wave-private). Issue order [B,A,N] fixed by
// sched_barrier(0); steady vmcnt(5), tail 4,4,0 (hand-simulated FIFO ledger).
// nbr pre-merged with mask (-1 = masked -> gather a zeroed 128B row).
// ---------------------------------------------------------------------------
__device__ __forceinline__ void conv_core(
    const short* __restrict__ xin, const int* __restrict__ nbrm,
    const short* __restrict__ wfrag, const short* __restrict__ zrow,
    short* As_, short* Bs_, int* Ns_,
    int n, int lane, int wid, long wrow0, f32x4 acc[2][4])
{
  auto issueA = [&](int slot, const int p[4]){
    short* dst = As_ + (wid*2 + slot)*2048;
    #pragma unroll
    for (int j=0;j<4;j++){
      int r = j*8 + (lane>>3);
      int s = (lane&7) ^ (r&7);              // pre-swizzled global source
      const short* src = (p[j]<0) ? (zrow + s*8) : (xin + (long)p[j]*64 + s*8);
      gld16(src, dst + j*512);
    }
  };
  auto issueB = [&](int k){
    short* dst = Bs_ + (k&1)*4096 + wid*1024;
    #pragma unroll
    for (int j=0;j<2;j++)
      gld16(wfrag + ((long)k*512 + wid*128 + j*64 + lane)*8, dst + j*512);
  };
  auto issueN = [&](int k){
    int* dst = Ns_ + ((k&3)*4 + wid)*64;
    long R = wrow0 + (lane&31);
    if (R >= n) R = n-1;                     // clamp; results discarded later
    gld4(nbrm + R*27 + k, dst);
  };
  // prologue: mimic iters -2 [A(0) N(2)] and -1 [B(0) A(1) N(3)]
  int p0[4], p1[4];
  #pragma unroll
  for (int j=0;j<4;j++){
    long R = wrow0 + j*8 + (lane>>3);
    bool v = R < n;
    long Rc = v ? R : (long)(n-1);
    p0[j] = v ? nbrm[Rc*27+0] : -1;
    p1[j] = v ? nbrm[Rc*27+1] : -1;
  }
  issueA(0, p0); __builtin_amdgcn_sched_barrier(0);
  issueN(2);     __builtin_amdgcn_sched_barrier(0);
  issueB(0);     __builtin_amdgcn_sched_barrier(0);
  issueA(1, p1); __builtin_amdgcn_sched_barrier(0);
  issueN(3);     __builtin_amdgcn_sched_barrier(0);
  #pragma unroll
  for (int k=0;k<27;k++){
    // FIFO ledger: retire through own B(k) quarter (+A(k), N(k+2) older).
    if (k<24)      asm volatile("s_waitcnt vmcnt(5)" ::: "memory");
    else if (k<26) asm volatile("s_waitcnt vmcnt(4)" ::: "memory");
    else           asm volatile("s_waitcnt vmcnt(0)" ::: "memory");
    __builtin_amdgcn_sched_barrier(0);
    __builtin_amdgcn_s_barrier();            // publish all waves' B(k) quarters
    int pn[4];
    if (k<25){
      const int* sN = Ns_ + (((k+2)&3)*4 + wid)*64;
      #pragma unroll
      for (int j=0;j<4;j++) pn[j] = sN[j*8 + (lane>>3)];
    }
    bf16x8 a[2][2];
    const bf16x8* Aw = (const bf16x8*)(As_ + (wid*2 + (k&1))*2048);
    #pragma unroll
    for (int rt=0;rt<2;rt++){
      int r = rt*16 + (lane&15);
      #pragma unroll
      for (int h=0;h<2;h++)
        a[rt][h] = Aw[(r*8 + h*4 + (lane>>4)) ^ (r&7)];
    }
    bf16x8 b[4][2];
    const bf16x8* Bw = (const bf16x8*)(Bs_ + (k&1)*4096);
    #pragma unroll
    for (int ct=0;ct<4;ct++)
    #pragma unroll
    for (int h=0;h<2;h++)
      b[ct][h] = Bw[(ct*2+h)*64 + lane];
    asm volatile("s_waitcnt lgkmcnt(0)" ::: "memory");
    __builtin_amdgcn_sched_barrier(0);
    if (k<26){ issueB(k+1); __builtin_amdgcn_sched_barrier(0); }
    if (k<25){ issueA(k&1, pn); __builtin_amdgcn_sched_barrier(0); }
    if (k<23){ issueN(k+4); __builtin_amdgcn_sched_barrier(0); }
    #pragma unroll
    for (int ct=0;ct<4;ct++)
    #pragma unroll
    for (int h=0;h<2;h++){
      acc[0][ct] = MFMA(a[0][h], b[ct][h], acc[0][ct]);
      acc[1][ct] = MFMA(a[1][h], b[ct][h], acc[1][ct]);
    }
  }
}

// sparse conv: y[i] = sum_k x[nbrm[i,k]] @ W[k] + b  (+resid) -> prelu
__global__ __launch_bounds__(256,3) void k_conv(
    const short* __restrict__ xin, const int* __restrict__ nbrm,
    const short* __restrict__ wfrag, const float* __restrict__ bias,
    const float* __restrict__ alphap, const short* __restrict__ resid,
    short* __restrict__ outb, float* __restrict__ outf, int n,
    const short* __restrict__ zrow)
{
  __shared__ __align__(16) short As_[16384];   // 4 waves x 2 slots x 4KB
  __shared__ __align__(16) short Bs_[8192];    // 2 slots x 8KB (block-shared)
  __shared__ __align__(16) int   Ns_[1024];    // 4 slots x 4 waves x 64
  int t=threadIdx.x, lane=t&63, wid=t>>6;
  long wrow0 = (long)blockIdx.x*128 + wid*32;
  f32x4 acc[2][4];
  #pragma unroll
  for (int a_=0;a_<2;a_++)
  #pragma unroll
  for (int b_=0;b_<4;b_++) acc[a_][b_] = f32x4{0.f,0.f,0.f,0.f};
  conv_core(xin, nbrm, wfrag, zrow, As_, Bs_, Ns_, n, lane, wid, wrow0, acc);
  float al = alphap ? alphap[0] : 0.f;
  #pragma unroll
  for (int rt=0;rt<2;rt++)
  #pragma unroll
  for (int ct=0;ct<4;ct++){
    int col = ct*16 + (lane&15);
    float bc = bias[col];
    #pragma unroll
    for (int q=0;q<4;q++){
      long rr = wrow0 + rt*16 + (lane>>4)*4 + q;
      if (rr < n){
        float v = acc[rt][ct][q] + bc;
        if (resid) v += b2f(resid[rr*64+col]);
        if (alphap) v = v>=0.f ? v : al*v;
        outb[rr*64+col] = f2b(v);
        if (outf) outf[rr*64+col] = v;
      }
    }
  }
}

// fused p = r0 @ Wl0 + bl0 (64->512) + child-gather scatter to tmp[M,64].
__global__ __launch_bounds__(256) void k_linscatter(
    const short* __restrict__ r0b, const short* __restrict__ wl0f,
    const float* __restrict__ bl0, const int* __restrict__ inv,
    short* __restrict__ tmpb, int n)
{
  __shared__ bf16x8 Au[1024];
  int t=threadIdx.x, lane=t&63, wid=t>>6, wrow=wid>>1, wcol=wid&1;
  long row0=(long)blockIdx.x*128;
  int sr=t>>1, sh=t&1;
  long r=row0+sr;
  bf16x8 z = {0,0,0,0,0,0,0,0};
  const bf16x8* s = (const bf16x8*)(r0b + r*64 + sh*32);
  int ub = sr*8+sh*4;
  #pragma unroll
  for (int j=0;j<4;j++) Au[(ub+j)^(sr&7)] = (r<n)? s[j] : z;
  __syncthreads();
  bf16x8 a[4][2];
  #pragma unroll
  for (int rt=0;rt<4;rt++){
    int rr = wrow*64 + rt*16 + (lane&15);
    #pragma unroll
    for (int ks=0;ks<2;ks++)
      a[rt][ks] = Au[(rr*8 + ks*4 + (lane>>4)) ^ (rr&7)];
  }
  const bf16x8* wf = (const bf16x8*)wl0f;
  for (int cb=0;cb<8;cb++){
    f32x4 acc[4][2];
    #pragma unroll
    for (int a_=0;a_<4;a_++)
    #pragma unroll
    for (int b_=0;b_<2;b_++) acc[a_][b_] = f32x4{0.f,0.f,0.f,0.f};
    #pragma unroll
    for (int ct=0;ct<2;ct++)
    #pragma unroll
    for (int ks=0;ks<2;ks++){
      bf16x8 b = wf[cb*512 + ((wcol*2+ct)*2+ks)*64 + lane];
      #pragma unroll
      for (int rt=0;rt<4;rt++) acc[rt][ct] = MFMA(a[rt][ks], b, acc[rt][ct]);
    }
    #pragma unroll
    for (int rt=0;rt<4;rt++)
    #pragma unroll
    for (int q=0;q<4;q++){
      long parent = row0 + wrow*64 + rt*16 + (lane>>4)*4 + q;
      if (parent < n){
        int m = inv[parent*8 + cb];
        if (m >= 0){
          #pragma unroll
          for (int ct=0;ct<2;ct++){
            int col = wcol*32 + ct*16 + (lane&15);
            tmpb[(long)m*64 + col] = f2b(acc[rt][ct][q] + bl0[cb*64+col]);
          }
        }
      }
    }
  }
}

// fused pred[1]: pipelined conv (M rows) + prelu -> wave-private LDS q tile,
// then logits = q @ Wl1 + bl1, log_softmax + CE (no q / logits in HBM).
__global__ __launch_bounds__(256,3) void k_convloss(
    const short* __restrict__ xin, const int* __restrict__ nbrm,
    const short* __restrict__ wfrag, const float* __restrict__ bias,
    const float* __restrict__ alphap, const short* __restrict__ wl1f,
    const float* __restrict__ bl1, const void* __restrict__ bins0,
    float* __restrict__ ce_out, int n, const int* __restrict__ flagp,
    const short* __restrict__ zrow)
{
  __shared__ __align__(16) short As_[16384];
  __shared__ __align__(16) short Bs_[8192];
  __shared__ __align__(16) int   Ns_[1024];
  int flag = *flagp;
  int t=threadIdx.x, lane=t&63, wid=t>>6;
  long wrow0 = (long)blockIdx.x*128 + wid*32;
  f32x4 acc[2][4];
  #pragma unroll
  for (int a_=0;a_<2;a_++)
  #pragma unroll
  for (int b_=0;b_<4;b_++) acc[a_][b_] = f32x4{0.f,0.f,0.f,0.f};
  conv_core(xin, nbrm, wfrag, zrow, As_, Bs_, Ns_, n, lane, wid, wrow0, acc);
  // q = prelu(conv + bias) -> wave-private LDS tile (reuse wave's slot 0;
  // pipeline fully drained by final vmcnt(0)).
  float al = alphap[0];
  short* Qs = As_ + (wid*2)*2048;
  #pragma unroll
  for (int rt=0;rt<2;rt++)
  #pragma unroll
  for (int ct=0;ct<4;ct++){
    int col = ct*16 + (lane&15);
    float bc = bias[col];
    #pragma unroll
    for (int q=0;q<4;q++){
      int lrow = rt*16 + (lane>>4)*4 + q;
      float v = acc[rt][ct][q] + bc;
      v = v>=0.f ? v : al*v;
      Qs[(lrow*8 + ((col>>3)^(lrow&7)))*8 + (col&7)] = f2b(v);
    }
  }
  // loss: per wave, 2 row-tiles of 16; wl1 frags from global (L2-resident).
  const bf16x8* wl = (const bf16x8*)wl1f;
  const bf16x8* Qw = (const bf16x8*)Qs;
  float ce_local = 0.f;
  int c0=lane&15, gq=lane>>4;
  #pragma unroll
  for (int rt=0; rt<2; rt++){
    int rr = rt*16 + (lane&15);
    bf16x8 a0 = Qw[(rr*8 + (lane>>4)) ^ (rr&7)];
    bf16x8 a1 = Qw[(rr*8 + 4 + (lane>>4)) ^ (rr&7)];
    f32x4 acl[16];
    #pragma unroll
    for (int ct=0;ct<16;ct++) acl[ct]=f32x4{0.f,0.f,0.f,0.f};
    #pragma unroll
    for (int ct=0;ct<16;ct++){
      acl[ct]=MFMA(a0, wl[(ct*2)*64+lane],   acl[ct]);
      acl[ct]=MFMA(a1, wl[(ct*2+1)*64+lane], acl[ct]);
    }
    #pragma unroll
    for (int q=0;q<4;q++){
      long rowg = wrow0 + rt*16 + gq*4 + q;
      bool valid = rowg < (long)n;
      int oct=-1;
      if (valid){
        #pragma unroll
        for (int j=0;j<8;j++) if (rd_mask(bins0, rowg*8+j, flag)) oct += (1<<j);
      }
      float lg[16]; float mx=-3e38f;
      #pragma unroll
      for (int ct=0;ct<16;ct++){
        int col=ct*16+c0;
        float v = acl[ct][q] + ((col<255)? bl1[col] : -1e30f);
        lg[ct]=v; mx=fmaxf(mx,v);
      }
      #pragma unroll
      for (int d=1; d<16; d<<=1) mx = fmaxf(mx, __shfl_xor(mx,d));
      float sm=0.f, selv=0.f;
      #pragma unroll
      for (int ct=0;ct<16;ct++){
        sm += __expf(lg[ct]-mx);
        if (valid && ct==(oct>>4) && c0==(oct&15)) selv=lg[ct];
      }
      #pragma unroll
      for (int d=1; d<16; d<<=1) sm += __shfl_xor(sm,d);
      if (valid && c0==(oct&15)) ce_local += mx + __logf(sm) - selv;
    }
  }
  #pragma unroll
  for (int d=1; d<64; d<<=1) ce_local += __shfl_xor(ce_local,d);
  if (lane==0) atomicAdd(ce_out, ce_local);
}

__global__ void k_final(const float* __restrict__ ce, float* __restrict__ out, float scale){
  if (threadIdx.x==0 && blockIdx.x==0) out[0] = ce[0]*scale;
}

extern "C" void kernel_launch(void* const* d_in, const int* in_sizes, int n_in,
                              void* d_out, int out_size, void* d_ws, size_t ws_size,
                              hipStream_t stream) {
  const int N = in_sizes[0] / 64;      // 150000
  const int M = in_sizes[3];           // 600000
  char* ws = (char*)d_ws;
  int*   flag = (int*)ws;
  float* ce   = (float*)(ws + 64);
  short* zrow = (short*)(ws + 128);            // 128B zero row
  short* wconvf = (short*)(ws + 256);          // 4 x 110592 shorts
  short* wb1f = wconvf;
  short* wb2f = wb1f + 110592;
  short* wp0f = wb2f + 110592;
  short* wp1f = wp0f + 110592;
  short* wdecf= wp1f + 110592;                 // 8192
  short* wl0f = wdecf + 8192;                  // 32768
  short* wl1f = wl0f + 32768;                  // 16384  -> ends < 1 MB
  int*   inv  = (int*)(ws + ((size_t)1<<20));  // N*8 ints (4.8 MB)
  size_t off_act = (((size_t)1<<20) + (size_t)N*8*4 + 4095) & ~(size_t)4095;
  short* xb   = (short*)(ws + off_act);        // [N,64] bf16 (19.2 MB)
  short* h1b  = xb + (size_t)N*64;
  short* recb = h1b + (size_t)N*64;            // inside tmpb span; dead before overwrite
  short* r0b  = xb;                            // alias: xb dead after conv2
  short* tmpb = h1b;                           // [M,64] bf16 (76.8 MB); h1b/recb dead
  // total ws footprint ~= off_act + 19.2MB + 76.8MB ~= 102 MB

  int* nbr0 = (int*)d_in[4];                   // merged in-place (restored per launch)
  int* nbr1 = (int*)d_in[6];
  const float* a_dec = (const float*)d_in[11];
  int gN = (N+127)/128, gM = (M+127)/128;

  k_detect<<<1,64,0,stream>>>(d_in[5], flag, ce, (int*)zrow);
  k_merge<<<(N*27+255)/256,256,0,stream>>>(nbr0, d_in[5], N*27, flag);
  k_merge<<<(M*27+255)/256,256,0,stream>>>(nbr1, d_in[7], M*27, flag);
  k_prep<<<1952,256,0,stream>>>(
      (const float*)d_in[9], (const float*)d_in[12], (const float*)d_in[15],
      (const float*)d_in[18], (const float*)d_in[23], (const float*)d_in[21],
      (const float*)d_in[26], wdecf, wconvf, wl0f, wl1f);
  k_inv_init<<<(N*8+255)/256,256,0,stream>>>(inv, N*8);
  k_inv_fill<<<(M+255)/256,256,0,stream>>>((const int*)d_in[3], inv, M);
  k_dec<<<gN,256,0,stream>>>((const float*)d_in[0], (const float*)d_in[1], wdecf,
      (const float*)d_in[10], a_dec, xb, N);
  // block conv1
  k_conv<<<gN,256,0,stream>>>(xb, nbr0, wb1f,
      (const float*)d_in[13], (const float*)d_in[14], nullptr, h1b, nullptr, N, zrow);
  // block conv2 + residual(x) -> rec (bf16 + f32 to d_out)
  k_conv<<<gN,256,0,stream>>>(h1b, nbr0, wb2f,
      (const float*)d_in[16], (const float*)d_in[17], xb, recb, (float*)d_out, N, zrow);
  // pred[0] conv -> r0 (into xb slot)
  k_conv<<<gN,256,0,stream>>>(recb, nbr0, wp0f,
      (const float*)d_in[19], (const float*)d_in[20], nullptr, r0b, nullptr, N, zrow);
  // fused Linear(64->512) + child scatter -> tmp[M,64]
  k_linscatter<<<gN,256,0,stream>>>(r0b, wl0f, (const float*)d_in[22], inv, tmpb, N);
  // fused pred[1] conv + Wl1 + log_softmax + CE
  k_convloss<<<gM,256,0,stream>>>(tmpb, nbr1, wp1f,
      (const float*)d_in[24], (const float*)d_in[25], wl1f, (const float*)d_in[27],
      d_in[2], ce, M, flag, zrow);
  float scale = 1.4426950408889634f / (float)M;
  k_final<<<1,64,0,stream>>>(ce, (float*)d_out + (size_t)N*64, scale);
}